// Round 4
// baseline (262.544 us; speedup 1.0000x reference)
//
#include <hip/hip_runtime.h>

#define NCLS 80
#define NMK  32
#define NB   8400
#define MH_  160
#define MP   25600     // 160*160
#define IH   640
#define IW   640
#define KTOP 100
#define CONFT 0.4f
#define IOUT 0.7f
#define T_PRE 384        // NMS prefix handled by in-LDS bit-matrix (6 tiles of 64)
#define TW   (T_PRE/64)  // 6 u64 words per row

// ---------------- k_prep: score/argmax/key ----------------
__global__ __launch_bounds__(256) void k_prep(const float* __restrict__ det,
    float* __restrict__ key, int* __restrict__ cid, int* __restrict__ rank)
{
  int n = blockIdx.x*256 + threadIdx.x;
  if (n >= NB) return;
  float best = det[4*NB + n];
  int bc = 0;
  #pragma unroll 8
  for (int c = 1; c < NCLS; ++c){
    float v = det[(4+c)*NB + n];
    if (v > best){ best = v; bc = c; }   // strict > keeps FIRST max (matches jnp.argmax)
  }
  cid[n] = bc;
  key[n] = (best >= CONFT) ? -best : __builtin_inff();  // ascending argsort key; inf sorts last
  rank[n] = 0;
}

// ---------------- k_rank: O(N^2) stable rank, j-sliced 32 ways ----------------
__global__ __launch_bounds__(256) void k_rank(const float* __restrict__ key, int* __restrict__ rank)
{
  __shared__ float tk[256];
  int n = blockIdx.x*256 + threadIdx.x;
  float kn = (n < NB) ? key[n] : 0.f;
  int j0 = blockIdx.y * 263;           // 32 * 263 = 8416 >= 8400
  int j1 = min(j0 + 263, NB);
  int part = 0;
  for (int t0 = j0; t0 < j1; t0 += 256){
    int j = t0 + threadIdx.x;
    tk[threadIdx.x] = (j < NB) ? key[j] : 0.f;
    __syncthreads();
    int lim = min(256, j1 - t0);
    for (int jj = 0; jj < lim; ++jj){
      float kj = tk[jj];
      int jg = t0 + jj;
      part += ((kj < kn) || (kj == kn && jg < n)) ? 1 : 0;  // stable: ties by index
    }
    __syncthreads();
  }
  if (n < NB && part) atomicAdd(&rank[n], part);
}

// ---------------- k_scatter: build sorted arrays ----------------
__global__ __launch_bounds__(256) void k_scatter(const float* __restrict__ det,
    const int* __restrict__ cid, const int* __restrict__ rank,
    int* __restrict__ perm, int* __restrict__ scid, float4* __restrict__ sbox)
{
  int n = blockIdx.x*256 + threadIdx.x;
  if (n >= NB) return;
  int r = rank[n];
  perm[r] = n;
  scid[r] = cid[n];
  float4 b;
  b.x = det[0*NB + n]; b.y = det[1*NB + n];
  b.z = det[2*NB + n]; b.w = det[3*NB + n];
  sbox[r] = b;
}

// ---------------- k_nms2: fused nvalid-count + in-LDS supmat + greedy ----------------
__global__ __launch_bounds__(1024) void k_nms2(const float* __restrict__ key,
    const float4* __restrict__ sbox, const int* __restrict__ scid, const int* __restrict__ perm,
    int* __restrict__ selorig, int4* __restrict__ selbox, int* __restrict__ selcid,
    int* __restrict__ nsel)
{
  __shared__ __align__(16) unsigned long long lsup[T_PRE*TW];  // 18 KB
  __shared__ int keptpos[KTOP];
  __shared__ int s_nv;
  __shared__ int s_found;
  const int tid  = threadIdx.x;
  const int lane = tid & 63;
  const int wv   = tid >> 6;       // 16 waves
  if (tid == 0) s_nv = 0;
  __syncthreads();
  // Phase A: count valid (finite keys); count is permutation-invariant
  {
    int cnt = 0;
    for (int n = tid; n < NB; n += 1024){
      unsigned long long bal = __ballot(key[n] < 1e38f);
      if (lane == 0) cnt += (int)__popcll(bal);
    }
    if (lane == 0 && cnt) atomicAdd(&s_nv, cnt);
  }
  // Phase B: suppression bit-matrix tiles, one wave per 64x64 tile
  for (int t = wv; t < TW*TW; t += 16){
    const int ti = t / TW, tj = t % TW;
    float4 bj = sbox[tj*64 + lane];
    float aj = (bj.z - bj.x) * (bj.w - bj.y);
    float4 bi_all = sbox[ti*64 + lane];
    float ai_all  = (bi_all.z - bi_all.x) * (bi_all.w - bi_all.y);
    const int jg = tj*64 + lane;
    unsigned long long myrow = 0ull;
    #pragma unroll 4
    for (int ii = 0; ii < 64; ++ii){
      float bix = __shfl(bi_all.x, ii, 64);
      float biy = __shfl(bi_all.y, ii, 64);
      float biz = __shfl(bi_all.z, ii, 64);
      float biw = __shfl(bi_all.w, ii, 64);
      float ai  = __shfl(ai_all,  ii, 64);
      float ix1 = fmaxf(bix, bj.x), iy1 = fmaxf(biy, bj.y);
      float ix2 = fminf(biz, bj.z), iy2 = fminf(biw, bj.w);
      float inter = fmaxf(ix2 - ix1, 0.f) * fmaxf(iy2 - iy1, 0.f);
      bool sup = (jg > ti*64 + ii) && (inter / (ai + aj - inter) >= IOUT);  // exact ref fp32 expr
      unsigned long long bal = __ballot(sup);
      if (lane == ii) myrow = bal;
    }
    lsup[(ti*64 + lane)*TW + tj] = myrow;
  }
  __syncthreads();

  if (wv == 0){
    const int nv = s_nv;
    // keep-word init: sorted position valid <=> pos < nvalid (finite keys sort first)
    unsigned long long keepw = 0ull;
    if (lane < TW){
      int nbits = nv - lane*64;
      if (nbits >= 64) keepw = ~0ull;
      else if (nbits > 0) keepw = (1ull << nbits) - 1ull;
    }
    int found = 0;
    const int lim = min(nv, T_PRE);
    // Phase C: sequential candidate scan; static rows -> unconditional depth-2 prefetch
    unsigned long long r0 = (lane < TW) ? lsup[0*TW + lane] : 0ull;
    unsigned long long r1 = (lane < TW) ? lsup[1*TW + lane] : 0ull;
    for (int cand = 0; cand < lim; ++cand){
      unsigned long long r2 = (lane < TW && cand + 2 < T_PRE) ? lsup[(cand+2)*TW + lane] : 0ull;
      bool mine = (lane == (cand >> 6)) && ((keepw >> (cand & 63)) & 1ull);
      if (__ballot(mine)){                  // candidate still alive -> keep it
        if (lane == 0) keptpos[found] = cand;
        found++;
        if (found >= KTOP) break;           // 100th kept never needs to suppress
        keepw &= ~r0;                       // suppress its victims
      }
      r0 = r1; r1 = r2;
    }
    // Phase D: exact fallback over sorted positions >= T_PRE (never taken on this data)
    if (found < KTOP && nv > T_PRE){
      float4 kbA = make_float4(0.f,0.f,0.f,0.f);
      float4 kbB = make_float4(0.f,0.f,0.f,0.f);
      if (lane < found)      kbA = sbox[keptpos[lane]];
      if (lane + 64 < found) kbB = sbox[keptpos[lane + 64]];
      for (int j = T_PRE; j < nv && found < KTOP; ++j){
        float4 bj = sbox[j];
        float ajj = (bj.z - bj.x) * (bj.w - bj.y);
        bool s = false;
        if (lane < found){
          float ka = (kbA.z - kbA.x) * (kbA.w - kbA.y);
          float ix1 = fmaxf(kbA.x, bj.x), iy1 = fmaxf(kbA.y, bj.y);
          float ix2 = fminf(kbA.z, bj.z), iy2 = fminf(kbA.w, bj.w);
          float inter = fmaxf(ix2 - ix1, 0.f) * fmaxf(iy2 - iy1, 0.f);
          s = inter / (ka + ajj - inter) >= IOUT;
        }
        if (lane + 64 < found){
          float ka = (kbB.z - kbB.x) * (kbB.w - kbB.y);
          float ix1 = fmaxf(kbB.x, bj.x), iy1 = fmaxf(kbB.y, bj.y);
          float ix2 = fminf(kbB.z, bj.z), iy2 = fminf(kbB.w, bj.w);
          float inter = fmaxf(ix2 - ix1, 0.f) * fmaxf(iy2 - iy1, 0.f);
          s = s || (inter / (ka + ajj - inter) >= IOUT);
        }
        if (!__ballot(s)){
          if (lane == 0) keptpos[found] = j;
          if (found < 64){ if (lane == found) kbA = bj; }
          else           { if (lane == found - 64) kbB = bj; }
          found++;
        }
      }
    }
    if (lane == 0) s_found = found;
  }
  __syncthreads();
  const int ns = s_found;
  if (tid < ns){
    int si = keptpos[tid];
    float4 b = sbox[si];
    selorig[tid] = perm[si];
    selbox[tid]  = make_int4((int)b.x, (int)b.y, (int)b.z, (int)b.w); // trunc==floor, coords>=0
    selcid[tid]  = scid[si];
  }
  if (tid == 0) *nsel = ns;
}

// ---------------- k_mask: mask logits (32-dot) -> hard bits ----------------
__global__ __launch_bounds__(256) void k_mask(const float* __restrict__ det, const float* __restrict__ proto,
    const int* __restrict__ selorig, const int* __restrict__ nsel, unsigned int* __restrict__ hb)
{
  const int p    = blockIdx.x*256 + threadIdx.x;          // 0..25599
  const int lane = threadIdx.x & 63;
  const int wword = (blockIdx.x*256 + (threadIdx.x & ~63)) >> 5;  // 2 u32 words per wave
  float pr[NMK];
  #pragma unroll
  for (int m = 0; m < NMK; ++m) pr[m] = proto[m*MP + p];
  const int ns = *nsel;
  const int k0 = blockIdx.y * 25;
  for (int kk = 0; kk < 25; ++kk){
    int k = k0 + kk;
    if (k >= ns) break;                                   // uniform
    int so = selorig[k];
    const float* cf = det + 84*NB + so;                   // uniform -> scalar loads
    float acc = 0.f;
    #pragma unroll
    for (int m = 0; m < NMK; ++m) acc = fmaf(cf[(size_t)m*NB], pr[m], acc);
    unsigned long long bal = __ballot(acc > 0.f);         // hard = sigmoid>0.5 <=> logit>0
    if (lane == 0)  hb[k*800 + wword]     = (unsigned int)bal;
    if (lane == 32) hb[k*800 + wword + 1] = (unsigned int)(bal >> 32);
  }
}

// ---------------- k_paint: winner-per-pixel + coalesced one-hot row writes ----------------
__global__ __launch_bounds__(256) void k_paint(const int4* __restrict__ selbox, const int* __restrict__ selcid,
    const int* __restrict__ nsel, const unsigned int* __restrict__ hb, float* __restrict__ out)
{
  __shared__ int4  sbx[KTOP];
  __shared__ int   scd[KTOP];
  __shared__ short wcls[IW];
  __shared__ short clist[KTOP];
  __shared__ int   ccount;
  const int y = blockIdx.x;
  const int tid = threadIdx.x;
  const int ns = *nsel;
  if (tid < ns){ sbx[tid] = selbox[tid]; scd[tid] = selcid[tid]; }
  if (tid == 0) ccount = 0;
  __syncthreads();
  if (tid == 0){  // boxes intersecting this row, ascending k
    int m = 0;
    for (int k = 0; k < ns; ++k)
      if (y >= sbx[k].y && y < sbx[k].w) clist[m++] = (short)k;
    ccount = m;
  }
  __syncthreads();
  const int m = ccount;
  const int fyi = (y - 2) >> 2;                      // floor((y+0.5)/4 - 0.5)
  const int ylo = max(fyi, 0), yhi = min(fyi + 1, MH_ - 1);
  for (int x = tid; x < IW; x += 256){
    int cls = -1;
    for (int ci = m - 1; ci >= 0; --ci){             // highest k containing pixel wins
      int k = clist[ci];
      int4 b = sbx[k];
      if (x >= b.x && x < b.z){
        int fx = (x - 2) >> 2;
        int xlo = max(fx, 0), xhi = min(fx + 1, MH_ - 1);
        bool on = false;
        for (int ry = ylo; ry <= yhi; ++ry)
          for (int rx = xlo; rx <= xhi; ++rx){
            int pp = ry*MH_ + rx;
            on = on || ((hb[k*800 + (pp >> 5)] >> (pp & 31)) & 1u);
          }
        cls = on ? scd[k] : -1;                      // painted-zero == untouched-zero
        break;
      }
    }
    wcls[x] = (short)cls;
  }
  __syncthreads();
  // write 640*80 floats for this row, float4-coalesced (80 % 4 == 0 -> no pixel crossing)
  float4* o4 = (float4*)(out + (size_t)y * (IW*NCLS));
  for (int it = 0; it < 50; ++it){
    int f4 = it*256 + tid;         // 0..12799
    int x  = f4 / 20;
    int c  = (f4 % 20) * 4;
    int wc = wcls[x];
    float4 v;
    v.x = (wc == c    ) ? 1.f : 0.f;
    v.y = (wc == c + 1) ? 1.f : 0.f;
    v.z = (wc == c + 2) ? 1.f : 0.f;
    v.w = (wc == c + 3) ? 1.f : 0.f;
    o4[f4] = v;
  }
}

extern "C" void kernel_launch(void* const* d_in, const int* in_sizes, int n_in,
                              void* d_out, int out_size, void* d_ws, size_t ws_size,
                              hipStream_t stream)
{
  const float* det   = (const float*)d_in[0];   // (1,116,8400)
  const float* proto = (const float*)d_in[1];   // (1,32,160,160)
  float* out = (float*)d_out;                   // (1,640,640,80)
  char* w = (char*)d_ws;
  float*  key     = (float*)(w + 0);            // 33600
  int*    cid     = (int*)  (w + 33600);        // 33600
  int*    rank    = (int*)  (w + 67200);        // 33600
  int*    perm    = (int*)  (w + 100800);       // 33600
  int*    scid    = (int*)  (w + 134400);       // 33600
  float4* sbox    = (float4*)(w + 168000);      // 134400, 16B aligned
  int*    selorig = (int*)  (w + 302400);       // 400
  int4*   selbox  = (int4*) (w + 302800);       // 1600, 16B aligned
  int*    selcid  = (int*)  (w + 304400);       // 400
  int*    nsel    = (int*)  (w + 304800);       // 4
  unsigned int* hb = (unsigned int*)(w + 304816);  // 320000

  hipLaunchKernelGGL(k_prep,    dim3(33),      dim3(256),  0, stream, det, key, cid, rank);
  hipLaunchKernelGGL(k_rank,    dim3(33, 32),  dim3(256),  0, stream, key, rank);
  hipLaunchKernelGGL(k_scatter, dim3(33),      dim3(256),  0, stream, det, cid, rank, perm, scid, sbox);
  hipLaunchKernelGGL(k_nms2,    dim3(1),       dim3(1024), 0, stream, key, sbox, scid, perm,
                     selorig, selbox, selcid, nsel);
  hipLaunchKernelGGL(k_mask,    dim3(100, 4),  dim3(256),  0, stream, det, proto, selorig, nsel, hb);
  hipLaunchKernelGGL(k_paint,   dim3(640),     dim3(256),  0, stream, selbox, selcid, nsel, hb, out);
}

// Round 5
// 220.716 us; speedup vs baseline: 1.1895x; 1.1895x over previous
//
#include <hip/hip_runtime.h>

#define NCLS 80
#define NMK  32
#define NB   8400
#define MH_  160
#define MP   25600     // 160*160
#define IH   640
#define IW   640
#define KTOP 100
#define CONFT 0.4f
#define IOUT 0.7f
#define T_PRE 384        // NMS prefix handled by bit-matrix (6 tiles of 64)
#define TW   (T_PRE/64)  // 6 u64 words per row

// ---------------- k_prep: score/argmax/key + per-wave valid partials ----------------
__global__ __launch_bounds__(256) void k_prep(const float* __restrict__ det,
    float* __restrict__ key, int* __restrict__ cid, int* __restrict__ rank,
    int* __restrict__ nvp)   // nvp[33*4] per-wave partial counts (plain stores, no init needed)
{
  int n = blockIdx.x*256 + threadIdx.x;
  bool valid = false;
  if (n < NB){
    float best = det[4*NB + n];
    int bc = 0;
    #pragma unroll 8
    for (int c = 1; c < NCLS; ++c){
      float v = det[(4+c)*NB + n];
      if (v > best){ best = v; bc = c; }   // strict > keeps FIRST max (matches jnp.argmax)
    }
    cid[n] = bc;
    valid = best >= CONFT;
    key[n] = valid ? -best : __builtin_inff();  // ascending argsort key; inf sorts last
    rank[n] = 0;
  }
  unsigned long long bal = __ballot(valid);
  if ((threadIdx.x & 63) == 0)
    nvp[blockIdx.x*4 + (threadIdx.x >> 6)] = (int)__popcll(bal);
}

// ---------------- k_rank: O(N^2) stable rank, j-sliced 32 ways ----------------
__global__ __launch_bounds__(256) void k_rank(const float* __restrict__ key, int* __restrict__ rank)
{
  __shared__ float tk[256];
  int n = blockIdx.x*256 + threadIdx.x;
  float kn = (n < NB) ? key[n] : 0.f;
  int j0 = blockIdx.y * 263;           // 32 * 263 = 8416 >= 8400
  int j1 = min(j0 + 263, NB);
  int part = 0;
  for (int t0 = j0; t0 < j1; t0 += 256){
    int j = t0 + threadIdx.x;
    tk[threadIdx.x] = (j < NB) ? key[j] : 0.f;
    __syncthreads();
    int lim = min(256, j1 - t0);
    for (int jj = 0; jj < lim; ++jj){
      float kj = tk[jj];
      int jg = t0 + jj;
      part += ((kj < kn) || (kj == kn && jg < n)) ? 1 : 0;  // stable: ties by index
    }
    __syncthreads();
  }
  if (n < NB && part) atomicAdd(&rank[n], part);
}

// ---------------- k_scatter: build sorted arrays ----------------
__global__ __launch_bounds__(256) void k_scatter(const float* __restrict__ det,
    const int* __restrict__ cid, const int* __restrict__ rank,
    int* __restrict__ perm, int* __restrict__ scid, float4* __restrict__ sbox)
{
  int n = blockIdx.x*256 + threadIdx.x;
  if (n >= NB) return;
  int r = rank[n];
  perm[r] = n;
  scid[r] = cid[n];
  float4 b;
  b.x = det[0*NB + n]; b.y = det[1*NB + n];
  b.z = det[2*NB + n]; b.w = det[3*NB + n];
  sbox[r] = b;
}

// ---------------- k_supmat: pairwise suppression bits, one wave per 64x64 tile ----------------
__global__ __launch_bounds__(64) void k_supmat(const float4* __restrict__ sbox,
    unsigned long long* __restrict__ supmat)
{
  const int lane = threadIdx.x;
  const int ti = blockIdx.x;           // 0..TW-1
  const int tj = blockIdx.y;           // 0..TW-1
  float4 bj = sbox[tj*64 + lane];
  float aj = (bj.z - bj.x) * (bj.w - bj.y);
  float4 bi_all = sbox[ti*64 + lane];
  float ai_all  = (bi_all.z - bi_all.x) * (bi_all.w - bi_all.y);
  const int jg = tj*64 + lane;
  unsigned long long myrow = 0ull;
  #pragma unroll 4
  for (int ii = 0; ii < 64; ++ii){
    float bix = __shfl(bi_all.x, ii, 64);
    float biy = __shfl(bi_all.y, ii, 64);
    float biz = __shfl(bi_all.z, ii, 64);
    float biw = __shfl(bi_all.w, ii, 64);
    float ai  = __shfl(ai_all,  ii, 64);
    float ix1 = fmaxf(bix, bj.x), iy1 = fmaxf(biy, bj.y);
    float ix2 = fminf(biz, bj.z), iy2 = fminf(biw, bj.w);
    float inter = fmaxf(ix2 - ix1, 0.f) * fmaxf(iy2 - iy1, 0.f);
    bool sup = (jg > ti*64 + ii) && (inter / (ai + aj - inter) >= IOUT);  // exact ref fp32 expr
    unsigned long long bal = __ballot(sup);
    if (lane == ii) myrow = bal;
  }
  supmat[(size_t)(ti*64 + lane)*TW + tj] = myrow;
}

// ---------------- k_greedy: 18KB LDS copy + single-wave sequential scan ----------------
__global__ __launch_bounds__(1024) void k_greedy(const float4* __restrict__ sbox,
    const int* __restrict__ scid, const int* __restrict__ perm,
    const unsigned long long* __restrict__ supmat, const int* __restrict__ nvp,
    int* __restrict__ selorig, int4* __restrict__ selbox, int* __restrict__ selcid,
    int* __restrict__ nsel)
{
  __shared__ __align__(16) unsigned long long lsup[T_PRE*TW];  // 18 KB
  __shared__ int keptpos[KTOP];
  __shared__ int partial[192];
  __shared__ int s_nv;
  __shared__ int s_found;
  const int tid = threadIdx.x;
  // cooperative copy: 384*6 u64 = 1152 float4  (+ load nvalid partials)
  {
    const float4* g4 = (const float4*)supmat;
    float4* l4 = (float4*)lsup;
    for (int idx = tid; idx < (T_PRE*TW)/2; idx += 1024) l4[idx] = g4[idx];
    partial[tid & 191] = 0;                  // covers 0..191 (1024 threads wrap)
  }
  __syncthreads();
  if (tid < 132) partial[tid] = nvp[tid];
  __syncthreads();
  if (tid < 64){
    int s = partial[tid] + partial[tid + 64] + ((tid + 128 < 192) ? partial[tid + 128] : 0);
    #pragma unroll
    for (int sh = 32; sh > 0; sh >>= 1) s += __shfl_xor(s, sh, 64);
    if (tid == 0) s_nv = s;
  }
  __syncthreads();

  if (tid < 64){
    const int lane = tid;
    const int nv = s_nv;
    // keep-word init: sorted position valid <=> pos < nvalid (finite keys sort first)
    unsigned long long keepw = 0ull;
    if (lane < TW){
      int nbits = nv - lane*64;
      if (nbits >= 64) keepw = ~0ull;
      else if (nbits > 0) keepw = (1ull << nbits) - 1ull;
    }
    int found = 0;
    const int lim = min(nv, T_PRE);
    // sequential candidate scan; static rows -> unconditional depth-2 prefetch
    unsigned long long r0 = (lane < TW) ? lsup[0*TW + lane] : 0ull;
    unsigned long long r1 = (lane < TW) ? lsup[1*TW + lane] : 0ull;
    for (int cand = 0; cand < lim; ++cand){
      unsigned long long r2 = (lane < TW && cand + 2 < T_PRE) ? lsup[(cand+2)*TW + lane] : 0ull;
      bool mine = (lane == (cand >> 6)) && ((keepw >> (cand & 63)) & 1ull);
      if (__ballot(mine)){                  // candidate still alive -> keep it
        if (lane == 0) keptpos[found] = cand;
        found++;
        if (found >= KTOP) break;           // 100th kept never needs to suppress
        keepw &= ~r0;                       // suppress its victims
      }
      r0 = r1; r1 = r2;
    }
    // exact fallback over sorted positions >= T_PRE (never taken on this data)
    if (found < KTOP && nv > T_PRE){
      float4 kbA = make_float4(0.f,0.f,0.f,0.f);
      float4 kbB = make_float4(0.f,0.f,0.f,0.f);
      if (lane < found)      kbA = sbox[keptpos[lane]];
      if (lane + 64 < found) kbB = sbox[keptpos[lane + 64]];
      for (int j = T_PRE; j < nv && found < KTOP; ++j){
        float4 bj = sbox[j];
        float ajj = (bj.z - bj.x) * (bj.w - bj.y);
        bool s = false;
        if (lane < found){
          float ka = (kbA.z - kbA.x) * (kbA.w - kbA.y);
          float ix1 = fmaxf(kbA.x, bj.x), iy1 = fmaxf(kbA.y, bj.y);
          float ix2 = fminf(kbA.z, bj.z), iy2 = fminf(kbA.w, bj.w);
          float inter = fmaxf(ix2 - ix1, 0.f) * fmaxf(iy2 - iy1, 0.f);
          s = inter / (ka + ajj - inter) >= IOUT;
        }
        if (lane + 64 < found){
          float ka = (kbB.z - kbB.x) * (kbB.w - kbB.y);
          float ix1 = fmaxf(kbB.x, bj.x), iy1 = fmaxf(kbB.y, bj.y);
          float ix2 = fminf(kbB.z, bj.z), iy2 = fminf(kbB.w, bj.w);
          float inter = fmaxf(ix2 - ix1, 0.f) * fmaxf(iy2 - iy1, 0.f);
          s = s || (inter / (ka + ajj - inter) >= IOUT);
        }
        if (!__ballot(s)){
          if (lane == 0) keptpos[found] = j;
          if (found < 64){ if (lane == found) kbA = bj; }
          else           { if (lane == found - 64) kbB = bj; }
          found++;
        }
      }
    }
    if (lane == 0) s_found = found;
  }
  __syncthreads();
  const int ns = s_found;
  if (tid < ns){
    int si = keptpos[tid];
    float4 b = sbox[si];
    selorig[tid] = perm[si];
    selbox[tid]  = make_int4((int)b.x, (int)b.y, (int)b.z, (int)b.w); // trunc==floor, coords>=0
    selcid[tid]  = scid[si];
  }
  if (tid == 0) *nsel = ns;
}

// ---------------- k_mask: mask logits (32-dot) -> hard bits ----------------
__global__ __launch_bounds__(256) void k_mask(const float* __restrict__ det, const float* __restrict__ proto,
    const int* __restrict__ selorig, const int* __restrict__ nsel, unsigned int* __restrict__ hb)
{
  const int p    = blockIdx.x*256 + threadIdx.x;          // 0..25599
  const int lane = threadIdx.x & 63;
  const int wword = (blockIdx.x*256 + (threadIdx.x & ~63)) >> 5;  // 2 u32 words per wave
  float pr[NMK];
  #pragma unroll
  for (int m = 0; m < NMK; ++m) pr[m] = proto[m*MP + p];
  const int ns = *nsel;
  const int k0 = blockIdx.y * 10;
  for (int kk = 0; kk < 10; ++kk){
    int k = k0 + kk;
    if (k >= ns) break;                                   // uniform
    int so = selorig[k];
    const float* cf = det + 84*NB + so;                   // uniform -> scalar loads
    float acc = 0.f;
    #pragma unroll
    for (int m = 0; m < NMK; ++m) acc = fmaf(cf[(size_t)m*NB], pr[m], acc);
    unsigned long long bal = __ballot(acc > 0.f);         // hard = sigmoid>0.5 <=> logit>0
    if (lane == 0)  hb[k*800 + wword]     = (unsigned int)bal;
    if (lane == 32) hb[k*800 + wword + 1] = (unsigned int)(bal >> 32);
  }
}

// ---------------- k_paint: winner-per-pixel + coalesced one-hot row writes ----------------
__global__ __launch_bounds__(256) void k_paint(const int4* __restrict__ selbox, const int* __restrict__ selcid,
    const int* __restrict__ nsel, const unsigned int* __restrict__ hb, float* __restrict__ out)
{
  __shared__ int4  sbx[KTOP];
  __shared__ int   scd[KTOP];
  __shared__ short wcls[IW];
  __shared__ short clist[KTOP];
  __shared__ int   ccount;
  const int y = blockIdx.x;
  const int tid = threadIdx.x;
  const int ns = *nsel;
  if (tid < ns){ sbx[tid] = selbox[tid]; scd[tid] = selcid[tid]; }
  if (tid == 0) ccount = 0;
  __syncthreads();
  if (tid == 0){  // boxes intersecting this row, ascending k
    int m = 0;
    for (int k = 0; k < ns; ++k)
      if (y >= sbx[k].y && y < sbx[k].w) clist[m++] = (short)k;
    ccount = m;
  }
  __syncthreads();
  const int m = ccount;
  const int fyi = (y - 2) >> 2;                      // floor((y+0.5)/4 - 0.5)
  const int ylo = max(fyi, 0), yhi = min(fyi + 1, MH_ - 1);
  for (int x = tid; x < IW; x += 256){
    int cls = -1;
    for (int ci = m - 1; ci >= 0; --ci){             // highest k containing pixel wins
      int k = clist[ci];
      int4 b = sbx[k];
      if (x >= b.x && x < b.z){
        int fx = (x - 2) >> 2;
        int xlo = max(fx, 0), xhi = min(fx + 1, MH_ - 1);
        bool on = false;
        for (int ry = ylo; ry <= yhi; ++ry)
          for (int rx = xlo; rx <= xhi; ++rx){
            int pp = ry*MH_ + rx;
            on = on || ((hb[k*800 + (pp >> 5)] >> (pp & 31)) & 1u);
          }
        cls = on ? scd[k] : -1;                      // painted-zero == untouched-zero
        break;
      }
    }
    wcls[x] = (short)cls;
  }
  __syncthreads();
  // write 640*80 floats for this row, float4-coalesced (80 % 4 == 0 -> no pixel crossing)
  float4* o4 = (float4*)(out + (size_t)y * (IW*NCLS));
  for (int it = 0; it < 50; ++it){
    int f4 = it*256 + tid;         // 0..12799
    int x  = f4 / 20;
    int c  = (f4 % 20) * 4;
    int wc = wcls[x];
    float4 v;
    v.x = (wc == c    ) ? 1.f : 0.f;
    v.y = (wc == c + 1) ? 1.f : 0.f;
    v.z = (wc == c + 2) ? 1.f : 0.f;
    v.w = (wc == c + 3) ? 1.f : 0.f;
    o4[f4] = v;
  }
}

extern "C" void kernel_launch(void* const* d_in, const int* in_sizes, int n_in,
                              void* d_out, int out_size, void* d_ws, size_t ws_size,
                              hipStream_t stream)
{
  const float* det   = (const float*)d_in[0];   // (1,116,8400)
  const float* proto = (const float*)d_in[1];   // (1,32,160,160)
  float* out = (float*)d_out;                   // (1,640,640,80)
  char* w = (char*)d_ws;
  float*  key     = (float*)(w + 0);            // 33600
  int*    cid     = (int*)  (w + 33600);        // 33600
  int*    rank    = (int*)  (w + 67200);        // 33600
  int*    perm    = (int*)  (w + 100800);       // 33600
  int*    scid    = (int*)  (w + 134400);       // 33600
  float4* sbox    = (float4*)(w + 168000);      // 134400, 16B aligned
  int*    selorig = (int*)  (w + 302400);       // 400
  int4*   selbox  = (int4*) (w + 302800);       // 1600, 16B aligned
  int*    selcid  = (int*)  (w + 304400);       // 400
  int*    nsel    = (int*)  (w + 304800);       // 4
  int*    nvp     = (int*)  (w + 304832);       // 528 (33 blocks * 4 waves)
  unsigned int* hb = (unsigned int*)(w + 305408);              // 320000
  unsigned long long* supmat = (unsigned long long*)(w + 625408); // 18432

  hipLaunchKernelGGL(k_prep,    dim3(33),      dim3(256),  0, stream, det, key, cid, rank, nvp);
  hipLaunchKernelGGL(k_rank,    dim3(33, 32),  dim3(256),  0, stream, key, rank);
  hipLaunchKernelGGL(k_scatter, dim3(33),      dim3(256),  0, stream, det, cid, rank, perm, scid, sbox);
  hipLaunchKernelGGL(k_supmat,  dim3(TW, TW),  dim3(64),   0, stream, sbox, supmat);
  hipLaunchKernelGGL(k_greedy,  dim3(1),       dim3(1024), 0, stream, sbox, scid, perm, supmat, nvp,
                     selorig, selbox, selcid, nsel);
  hipLaunchKernelGGL(k_mask,    dim3(100, 10), dim3(256),  0, stream, det, proto, selorig, nsel, hb);
  hipLaunchKernelGGL(k_paint,   dim3(640),     dim3(256),  0, stream, selbox, selcid, nsel, hb, out);
}